// Round 12
// baseline (137.883 us; speedup 1.0000x reference)
//
#include <hip/hip_runtime.h>
#include <math.h>

// Problem constants
#define S_ 500
#define D_ 768
#define K_ 16
#define R_ 256
#define P_ 64
#define NT 12  // 768 / BK, BK = 64

typedef unsigned short ushort_t;
typedef __attribute__((ext_vector_type(8))) short short8;   // 8 x bf16 (4 VGPRs)
typedef __attribute__((ext_vector_type(4))) float floatx4;  // MFMA accumulator

__device__ inline ushort_t f2bf(float x) {  // fp32 -> bf16, round-nearest-even
  unsigned int u = __float_as_uint(x);
  u += 0x7fffu + ((u >> 16) & 1u);
  return (ushort_t)(u >> 16);
}

#define GLD_LDS16(g, l)                                                        \
  __builtin_amdgcn_global_load_lds(                                            \
      (const __attribute__((address_space(1))) void*)(g),                      \
      (__attribute__((address_space(3))) void*)(l), 16, 0, 0)

// raw barrier + counted vmcnt: r0-proven combo for ALL-gld_lds staging
#define ASM_BARRIER asm volatile("s_barrier" ::: "memory")
#define WAIT_VM6 asm volatile("s_waitcnt vmcnt(6)" ::: "memory")
#define WAIT_VM4 asm volatile("s_waitcnt vmcnt(4)" ::: "memory")
#define WAIT_VM0 asm volatile("s_waitcnt vmcnt(0)" ::: "memory")

// ---------------------------------------------------------------------------
// prep: fused convert_we + transpose_w.  (r0/r2/r11-proven, byte-copy.)
// ---------------------------------------------------------------------------
__global__ __launch_bounds__(256) void prep(const float* __restrict__ WE,
                                            const float* __restrict__ W,
                                            ushort_t* __restrict__ WEb,
                                            ushort_t* __restrict__ Wt) {
  const int t = threadIdx.x;
  if (blockIdx.x < 384) {
    int gid = blockIdx.x * 256 + t;  // 98304 threads, 4 elems each
    int row = gid / 192;             // 192 float4 per row
    ushort4 o = {0, 0, 0, 0};
    if (row < S_) {
      float4 v = *(const float4*)(WE + (size_t)gid * 4);
      o.x = f2bf(v.x); o.y = f2bf(v.y); o.z = f2bf(v.z); o.w = f2bf(v.w);
    }
    *(ushort4*)(WEb + (size_t)gid * 4) = o;
    return;
  }
  __shared__ float tile[64][68];
  const int tb = blockIdx.x - 384;          // 0..2303
  const int n0 = (tb % 192) * 64, d0 = (tb / 192) * 64;
  {
    const int r = t >> 2, cbase = (t & 3) * 16;
#pragma unroll
    for (int i = 0; i < 4; i++) {
      float4 v = *(const float4*)(W + (size_t)(d0 + r) * 12288 + n0 + cbase + i * 4);
      *(float4*)&tile[r][cbase + i * 4] = v;
    }
  }
  __syncthreads();
  {
    const int bc = t & 15;
    const int br4 = (t >> 4) * 4;
    float4 tv[4];
#pragma unroll
    for (int ii = 0; ii < 4; ii++)
      tv[ii] = *(const float4*)&tile[bc * 4 + ii][br4];
#pragma unroll
    for (int j = 0; j < 4; j++) {
      ushort4 o;
      o.x = f2bf(((const float*)&tv[0])[j]);
      o.y = f2bf(((const float*)&tv[1])[j]);
      o.z = f2bf(((const float*)&tv[2])[j]);
      o.w = f2bf(((const float*)&tv[3])[j]);
      *(ushort4*)(Wt + (size_t)(n0 + br4 + j) * 768 + d0 + bc * 4) = o;
    }
  }
}

// ---------------------------------------------------------------------------
// mm0_bt64: proj = WEb @ Wt^T.  (r11-proven, byte-identical.)  64m x 128n,
// 48 KB LDS, grid (96,8) = 768 = 3/CU exact; 6 gld_lds/thread/iter, vmcnt(6).
// ---------------------------------------------------------------------------
__global__ __launch_bounds__(256, 3) void mm0_bt64(const ushort_t* __restrict__ A,
                                                   const ushort_t* __restrict__ Bm,
                                                   ushort_t* __restrict__ C) {
  __shared__ ushort_t As[2][2][64 * 32];   // [buf][sub][row][32k], 16 KB
  __shared__ ushort_t Bs[2][2][128 * 32];  // 32 KB
  const int tid = threadIdx.x;
  const int wave = tid >> 6, lane = tid & 63;
  const int m0 = blockIdx.y * 64, n0 = blockIdx.x * 128;
  const int wn = wave * 32;  // wave owns 64m x 32n
  const int col = lane & 15, quad = lane >> 4;

  floatx4 acc[4][2];
#pragma unroll
  for (int i = 0; i < 4; i++)
#pragma unroll
    for (int j = 0; j < 2; j++)
#pragma unroll
      for (int e = 0; e < 4; e++) acc[i][j][e] = 0.f;

  const ushort_t* ga0 = A + (size_t)(m0 + (tid >> 2)) * D_ + (tid & 3) * 8;
  const ushort_t* gb0 = Bm + (size_t)(n0 + (tid >> 2)) * D_ + (tid & 3) * 8;
  const int lbase = wave * 512;

#define ISSUE_T(t_, buf_)                                                      \
  do {                                                                         \
    const ushort_t* ga = ga0 + (t_)*64;                                        \
    const ushort_t* gb = gb0 + (t_)*64;                                        \
    GLD_LDS16(ga, &As[buf_][0][lbase]);                                        \
    GLD_LDS16(ga + 32, &As[buf_][1][lbase]);                                   \
    GLD_LDS16(gb, &Bs[buf_][0][lbase]);                                        \
    GLD_LDS16(gb + 32, &Bs[buf_][1][lbase]);                                   \
    GLD_LDS16(gb + 64 * D_, &Bs[buf_][0][2048 + lbase]);                       \
    GLD_LDS16(gb + 64 * D_ + 32, &Bs[buf_][1][2048 + lbase]);                  \
  } while (0)

  ISSUE_T(0, 0);
  for (int t = 0; t < NT; ++t) {
    const int cur = t & 1;
    if (t + 1 < NT) {
      ISSUE_T(t + 1, cur ^ 1);
      WAIT_VM6;  // own 6 loads for tile t retired; t+1's 6 stay in flight
    } else {
      WAIT_VM0;
    }
    ASM_BARRIER;
#pragma unroll
    for (int s = 0; s < 2; ++s) {
      short8 a[4], b[2];
#pragma unroll
      for (int i = 0; i < 4; i++)
        a[i] = *(const short8*)&As[cur][s][(i * 16 + col) * 32 + quad * 8];
#pragma unroll
      for (int j = 0; j < 2; j++)
        b[j] = *(const short8*)&Bs[cur][s][(wn + j * 16 + col) * 32 + quad * 8];
#pragma unroll
      for (int i = 0; i < 4; i++)
#pragma unroll
        for (int j = 0; j < 2; j++)
          acc[i][j] = __builtin_amdgcn_mfma_f32_16x16x32_bf16(b[j], a[i], acc[i][j], 0, 0, 0);
    }
    ASM_BARRIER;
  }
#undef ISSUE_T

#pragma unroll
  for (int i = 0; i < 4; i++) {
    int m = m0 + i * 16 + col;
#pragma unroll
    for (int j = 0; j < 2; j++) {
      int n = n0 + wn + j * 16 + quad * 4;
      ushort4 o;
      o.x = f2bf(acc[i][j][0]); o.y = f2bf(acc[i][j][1]);
      o.z = f2bf(acc[i][j][2]); o.w = f2bf(acc[i][j][3]);
      *(ushort4*)(C + (size_t)m * 12288 + n) = o;
    }
  }
}

// ---------------------------------------------------------------------------
// mm1_bt64: G = projb @ WEb^T.  RETILED r11->r12: 64m x 64n, 32 KB LDS,
// grid (8,128) = 1024 blocks = EXACTLY 4 blocks/CU (16 waves/CU, was 2/CU =
// 8 waves -> latency-bound like r9's mm0).  Proven counted-vmcnt schedule,
// count re-derived: 4 gld_lds/thread/iter (A:2, B:2) -> vmcnt(4).
// XCD remap (bijective): q=lin&7 owns yb in [16q,16q+16), xb = (lin>>3)>>4;
// per-XCD A working set 16 x 96 KB = 1.5 MB < 4 MB L2; WEb (768 KB) cached.
// mfma(a,b): lane regs span k (G's contiguous dim) -> ushort4 scatter into
// bf16 G[s1][s2][16], guarded < 500.
// ---------------------------------------------------------------------------
__global__ __launch_bounds__(256, 4) void mm1_bt64(const ushort_t* __restrict__ A,
                                                   const ushort_t* __restrict__ Bm,
                                                   ushort_t* __restrict__ G) {
  __shared__ ushort_t As[2][2][64 * 32];  // 16 KB
  __shared__ ushort_t Bs[2][2][64 * 32];  // 16 KB
  const int tid = threadIdx.x;
  const int wave = tid >> 6, lane = tid & 63;
  const int lin = blockIdx.x + (blockIdx.y << 3);
  const int q = lin & 7, r = lin >> 3;  // r 0..127
  const int yb = q * 16 + (r & 15);     // 0..127
  const int xb = r >> 4;                // 0..7
  const int m0 = yb * 64, n0 = xb * 64;
  const int wm = (wave & 1) * 32, wn = (wave >> 1) * 32;
  const int col = lane & 15, quad = lane >> 4;

  floatx4 acc[2][2];
#pragma unroll
  for (int i = 0; i < 2; i++)
#pragma unroll
    for (int j = 0; j < 2; j++)
#pragma unroll
      for (int e = 0; e < 4; e++) acc[i][j][e] = 0.f;

  // thread t -> row t>>2 (0..63), 16-B slot t&3; per-wave linear LDS dest
  const ushort_t* ga0 = A + (size_t)(m0 + (tid >> 2)) * D_ + (tid & 3) * 8;
  const ushort_t* gb0 = Bm + (size_t)(n0 + (tid >> 2)) * D_ + (tid & 3) * 8;
  const int lbase = wave * 512;

#define ISSUE_T1(t_, buf_)                                                     \
  do {                                                                         \
    const ushort_t* ga = ga0 + (t_)*64;                                        \
    const ushort_t* gb = gb0 + (t_)*64;                                        \
    GLD_LDS16(ga, &As[buf_][0][lbase]);                                        \
    GLD_LDS16(ga + 32, &As[buf_][1][lbase]);                                   \
    GLD_LDS16(gb, &Bs[buf_][0][lbase]);                                        \
    GLD_LDS16(gb + 32, &Bs[buf_][1][lbase]);                                   \
  } while (0)

  ISSUE_T1(0, 0);
  for (int t = 0; t < NT; ++t) {
    const int cur = t & 1;
    if (t + 1 < NT) {
      ISSUE_T1(t + 1, cur ^ 1);
      WAIT_VM4;  // own 4 loads for tile t retired; t+1's 4 stay in flight
    } else {
      WAIT_VM0;
    }
    ASM_BARRIER;
#pragma unroll
    for (int s = 0; s < 2; ++s) {
      short8 a[2], b[2];
#pragma unroll
      for (int i = 0; i < 2; i++)
        a[i] = *(const short8*)&As[cur][s][(wm + i * 16 + col) * 32 + quad * 8];
#pragma unroll
      for (int j = 0; j < 2; j++)
        b[j] = *(const short8*)&Bs[cur][s][(wn + j * 16 + col) * 32 + quad * 8];
#pragma unroll
      for (int i = 0; i < 2; i++)
#pragma unroll
        for (int j = 0; j < 2; j++)
          acc[i][j] = __builtin_amdgcn_mfma_f32_16x16x32_bf16(a[i], b[j], acc[i][j], 0, 0, 0);
    }
    ASM_BARRIER;
  }
#undef ISSUE_T1

  // G[s1][s2][16] bf16: m = (s1,k); 16x16 m-tile is one s1, k = quad*4+reg
#pragma unroll
  for (int i = 0; i < 2; i++) {
    int s1 = (m0 + wm + i * 16) >> 4;
#pragma unroll
    for (int j = 0; j < 2; j++) {
      int s2 = n0 + wn + j * 16 + col;
      if (s1 < S_ && s2 < S_) {
        ushort4 o;
        o.x = f2bf(acc[i][j][0]); o.y = f2bf(acc[i][j][1]);
        o.z = f2bf(acc[i][j][2]); o.w = f2bf(acc[i][j][3]);
        *(ushort4*)(G + (((size_t)s1 * S_ + s2) << 4) + quad * 4) = o;
      }
    }
  }
}

// ---------------------------------------------------------------------------
// lse_kernel: out[r][k] = logsumexp over valid (p,q) of G[idx1[r,p]][idx2[r,q]][k]
// One block per r; 1024 threads (4 waves/SIMD — 2x latency hiding on random
// LLC gathers vs r11's 512); 1-exp online update.
// ---------------------------------------------------------------------------
__global__ __launch_bounds__(1024) void lse_kernel(const ushort_t* __restrict__ G,
                                                   const int* __restrict__ idx1,
                                                   const int* __restrict__ idx2,
                                                   const float* __restrict__ mask1,
                                                   const float* __restrict__ mask2,
                                                   float* __restrict__ out) {
  const int r = blockIdx.x;
  const int tid = threadIdx.x;
  __shared__ int b1[P_], b2[P_];
  __shared__ int s_len1, s_len2;
  __shared__ float wmx[16][K_], wsum[16][K_];

  if (tid < 64) {  // exactly wave 0
    float mv = mask1[r * P_ + tid];
    unsigned long long bal = __ballot(mv > 0.5f);
    if (tid == 0) s_len1 = (int)__popcll(bal);
    b1[tid] = idx1[r * P_ + tid] * (S_ * K_);
  } else if (tid < 128) {  // exactly wave 1
    int q = tid - 64;
    float mv = mask2[r * P_ + q];
    unsigned long long bal = __ballot(mv > 0.5f);
    if (q == 0) s_len2 = (int)__popcll(bal);
    b2[q] = idx2[r * P_ + q] * K_;
  }
  __syncthreads();
  const int len2 = s_len2;
  const int total = s_len1 * len2;

  float m[K_], s[K_];
#pragma unroll
  for (int k = 0; k < K_; k++) { m[k] = -3.0e38f; s[k] = 0.f; }

  for (int i = tid; i < total; i += 1024) {
    int p = i / len2;
    int q = i - p * len2;
    const uint4* g4 = (const uint4*)(G + b1[p] + b2[q]);  // 16 bf16 = 32 B
    uint4 w0 = g4[0], w1 = g4[1];
    unsigned int uu[8] = {w0.x, w0.y, w0.z, w0.w, w1.x, w1.y, w1.z, w1.w};
    float z[K_];
#pragma unroll
    for (int h = 0; h < 8; h++) {
      z[2 * h + 0] = __uint_as_float(uu[h] << 16);
      z[2 * h + 1] = __uint_as_float(uu[h] & 0xffff0000u);
    }
#pragma unroll
    for (int k = 0; k < K_; k++) {
      float d = z[k] - m[k];
      float e = __expf(-fabsf(d));
      bool up = d > 0.f;
      s[k] = up ? __fmaf_rn(s[k], e, 1.f) : (s[k] + e);
      m[k] = up ? z[k] : m[k];
    }
  }

#pragma unroll
  for (int off = 1; off < 64; off <<= 1) {
#pragma unroll
    for (int k = 0; k < K_; k++) {
      float mo = __shfl_xor(m[k], off, 64);
      float so = __shfl_xor(s[k], off, 64);
      float d = mo - m[k];
      float e = __expf(-fabsf(d));
      bool up = d > 0.f;
      s[k] = up ? __fmaf_rn(s[k], e, so) : __fmaf_rn(so, e, s[k]);
      m[k] = up ? mo : m[k];
    }
  }
  const int wave = tid >> 6, lane = tid & 63;
  if (lane == 0) {
#pragma unroll
    for (int k = 0; k < K_; k++) { wmx[wave][k] = m[k]; wsum[wave][k] = s[k]; }
  }
  __syncthreads();
  if (tid < K_) {
    float M = -3.0e38f, Ssum = 0.f;
#pragma unroll
    for (int w = 0; w < 16; w++) {
      float mo = wmx[w][tid], so = wsum[w][tid];
      float d = mo - M;
      float e = __expf(-fabsf(d));
      bool up = d > 0.f;
      Ssum = up ? __fmaf_rn(Ssum, e, so) : __fmaf_rn(so, e, Ssum);
      M = up ? mo : M;
    }
    out[r * K_ + tid] = M + __logf(Ssum);
  }
}

// ---------------------------------------------------------------------------
extern "C" void kernel_launch(void* const* d_in, const int* in_sizes, int n_in,
                              void* d_out, int out_size, void* d_ws, size_t ws_size,
                              hipStream_t stream) {
  const float* WE    = (const float*)d_in[0];  // [500][768]
  const float* W     = (const float*)d_in[1];  // [768][16][768]
  const int*   idx1  = (const int*)d_in[2];
  const int*   idx2  = (const int*)d_in[3];
  const float* mask1 = (const float*)d_in[4];
  const float* mask2 = (const float*)d_in[5];
  float* out = (float*)d_out;                  // [256][16]

  // workspace: WEb [512][768] bf16 | Wt [12288][768] bf16 |
  //            projb [512][12288] bf16 (== [8192][768]) | G [500][500][16] bf16
  ushort_t* WEb   = (ushort_t*)d_ws;
  ushort_t* Wt    = WEb + (size_t)512 * 768;
  ushort_t* projb = Wt + (size_t)12288 * 768;
  ushort_t* G     = projb + (size_t)8192 * 768;
  // total ~46 MB, 16B-aligned throughout

  prep<<<384 + 2304, 256, 0, stream>>>(WE, W, WEb, Wt);
  // proj[s][(k,e)] = WEb @ Wt^T : M=512, N=12288, tile 64x128, 768 blocks=3/CU
  mm0_bt64<<<dim3(96, 8), 256, 0, stream>>>(WEb, Wt, projb);
  // G[(s1,k)][s2] = projb @ WEb^T : M=8192, N=512, tile 64x64, 1024 blocks=4/CU
  mm1_bt64<<<dim3(8, 128), 256, 0, stream>>>(projb, WEb, G);
  lse_kernel<<<R_, 1024, 0, stream>>>(G, idx1, idx2, mask1, mask2, out);
}

// Round 13
// 131.512 us; speedup vs baseline: 1.0484x; 1.0484x over previous
//
#include <hip/hip_runtime.h>
#include <math.h>

// Problem constants
#define S_ 500
#define D_ 768
#define K_ 16
#define R_ 256
#define P_ 64
#define NT 12  // 768 / BK, BK = 64

typedef unsigned short ushort_t;
typedef __attribute__((ext_vector_type(8))) short short8;   // 8 x bf16 (4 VGPRs)
typedef __attribute__((ext_vector_type(4))) float floatx4;  // MFMA accumulator
typedef __attribute__((ext_vector_type(4))) float fx4;      // global fp32 vec load

__device__ inline ushort_t f2bf(float x) {  // fp32 -> bf16, round-nearest-even
  unsigned int u = __float_as_uint(x);
  u += 0x7fffu + ((u >> 16) & 1u);
  return (ushort_t)(u >> 16);
}

// packed fp32x2 -> bf16x2 (RNE), single VALU op
__device__ inline unsigned int cvtpk(float lo, float hi) {
  unsigned int r;
  asm("v_cvt_pk_bf16_f32 %0, %1, %2" : "=v"(r) : "v"(lo), "v"(hi));
  return r;
}

#define GLD_LDS16(g, l)                                                        \
  __builtin_amdgcn_global_load_lds(                                            \
      (const __attribute__((address_space(1))) void*)(g),                      \
      (__attribute__((address_space(3))) void*)(l), 16, 0, 0)

// raw barrier / fine-grained vmcnt (mm1's proven pattern)
#define ASM_BARRIER asm volatile("s_barrier" ::: "memory")
#define WAIT_VM6 asm volatile("s_waitcnt vmcnt(6)" ::: "memory")
#define WAIT_VM0 asm volatile("s_waitcnt vmcnt(0)" ::: "memory")

// mm0's schedule primitives (r5-proven pattern, counts re-derived)
#define CFENCE asm volatile("" ::: "memory")
#define BARRIER_SYNC                                                           \
  do { CFENCE; __builtin_amdgcn_s_barrier(); CFENCE; } while (0)
#define WAIT_VM10_F                                                            \
  do { asm volatile("s_waitcnt vmcnt(10)" ::: "memory");                       \
       __builtin_amdgcn_sched_barrier(0); } while (0)
#define WAIT_VM0_F                                                             \
  do { asm volatile("s_waitcnt vmcnt(0)" ::: "memory");                        \
       __builtin_amdgcn_sched_barrier(0); } while (0)
#define WAIT_LGKM0_F                                                           \
  do { asm volatile("s_waitcnt lgkmcnt(0)" ::: "memory");                      \
       __builtin_amdgcn_sched_barrier(0); } while (0)

// ---------------------------------------------------------------------------
// prep: WE fp32 [500][768] -> WEb bf16 [512][768] (pad rows = 0).  (r5-proven)
// ---------------------------------------------------------------------------
__global__ __launch_bounds__(256) void prep(const float* __restrict__ WE,
                                            ushort_t* __restrict__ WEb) {
  const int t = threadIdx.x;
  int gid = blockIdx.x * 256 + t;  // 98304 threads, 4 elems each
  int row = gid / 192;             // 192 float4 per row
  ushort4 o = {0, 0, 0, 0};
  if (row < S_) {
    float4 v = *(const float4*)(WE + (size_t)gid * 4);
    o.x = f2bf(v.x); o.y = f2bf(v.y); o.z = f2bf(v.z); o.w = f2bf(v.w);
  }
  *(ushort4*)(WEb + (size_t)gid * 4) = o;
}

// ---------------------------------------------------------------------------
// mm0_fused: proj = WEb @ W (fp32 B converted in staging).  64m x 128n,
// BK=64 dbuf, 48 KB LDS, grid (96,8) = 768 blocks = EXACTLY 3 blocks/CU
// (12 waves/CU; r10-measured best).  W-panel L2 locality: all 8 same-x
// blocks co-resident on one XCD (96 blocks/XCD = 32 CU x 3).
// Counted-vmcnt two-barrier schedule: per iter outstanding at the wait =
// A(t)2(oldest) + B(t+1)8 + A(t+1)2 = 12 -> vmcnt(10) retires exactly own
// A(t); 10 stay in flight across both barriers.
// A path: global_load_lds from WEb (linear LDS, 2 issues/thread/iter).
// B path: reg-stage 4x4 fp32 blocks, cvt_pk, ds_write_b64 into XOR-swizzled
// Bs (byte ^ ((nq&15)<<4)); read applies the same involution.
// mfma(b,a): lane regs span 4 consecutive C-cols -> ushort4 stores.
// C = proj bf16 [512][12288] (== proj2d [8192][768] in memory).
// ---------------------------------------------------------------------------
__global__ __launch_bounds__(256, 3) void mm0_fused(const ushort_t* __restrict__ A,
                                                    const float* __restrict__ Wf,
                                                    ushort_t* __restrict__ C) {
  __shared__ ushort_t As[2][2][64 * 32];   // [buf][ksub][row][32k'], 16 KB
  __shared__ ushort_t Bs[2][2][128 * 32];  // 32 KB, XOR-swizzled
  const int tid = threadIdx.x;
  const int wave = tid >> 6, lane = tid & 63;
  const int m0 = blockIdx.y * 64, n0 = blockIdx.x * 128;
  const int wn = wave * 32;  // wave owns 64m x 32n
  const int col = lane & 15, quad = lane >> 4;

  floatx4 acc[4][2];
#pragma unroll
  for (int i = 0; i < 4; i++)
#pragma unroll
    for (int j = 0; j < 2; j++)
#pragma unroll
      for (int e = 0; e < 4; e++) acc[i][j][e] = 0.f;

  // --- A staging: 1 gld_lds per 64x32 sub-buffer (256 thr x 16 B = 4 KB) ---
  // thread t: row t>>2 (0..63), 16B slot t&3; wave-uniform LDS base + lane*16
  const ushort_t* ga0 = A + (size_t)(m0 + (tid >> 2)) * D_ + (tid & 3) * 8;
#define ISSUE_A(t_, buf_)                                                      \
  do {                                                                         \
    const ushort_t* ga = ga0 + (t_)*64;                                        \
    GLD_LDS16(ga, &As[buf_][0][wave * 512]);                                   \
    GLD_LDS16(ga + 32, &As[buf_][1][wave * 512]);                              \
  } while (0)

  // --- B staging: thread owns 4x4 fp32 blocks (dqA, nq) h=0 and (dqA+8, nq)
  const int nq = tid & 31;   // row-quad 0..31: rows nq*4+j
  const int dqA = tid >> 5;  // k-quad 0..7:  k'' = dqA*4 + i (h=0); +32 (h=1)
  const float* gwA = Wf + (size_t)(dqA * 4) * 12288 + n0 + nq * 4;
  const float* gwB = gwA + (size_t)32 * 12288;

  fx4 bv[2][4];
#define LOADB(t_)                                                              \
  do {                                                                         \
    _Pragma("unroll") for (int i = 0; i < 4; i++) {                            \
      bv[0][i] = *(const fx4*)(gwA + (size_t)((t_)*64 + i) * 12288);           \
      bv[1][i] = *(const fx4*)(gwB + (size_t)((t_)*64 + i) * 12288);           \
    }                                                                          \
  } while (0)

  // Bs[sub][row n][k'' 0..31] bf16 (row stride 64 B), byte ^ ((nq&15)<<4)
#define WRITEB(buf_)                                                           \
  do {                                                                         \
    _Pragma("unroll") for (int h = 0; h < 2; h++)                              \
    _Pragma("unroll") for (int j = 0; j < 4; j++) {                            \
      int row = nq * 4 + j;                                                    \
      uint2 w;                                                                 \
      w.x = cvtpk(bv[h][0][j], bv[h][1][j]);                                   \
      w.y = cvtpk(bv[h][2][j], bv[h][3][j]);                                   \
      *(uint2*)((char*)&Bs[buf_][h][0] +                                       \
                ((row * 64 + dqA * 8) ^ ((nq & 15) << 4))) = w;                \
    }                                                                          \
  } while (0)

  // prologue: bv(0) issued BEFORE A(0) so WRITEB's compiler wait is vmcnt(2)
  // and A(0) stays in flight; lgkmcnt(0) publishes Bs[0] pre-barrier.
  LOADB(0);
  ISSUE_A(0, 0);
  WRITEB(0);
  WAIT_LGKM0_F;
  // loop invariant at iter t entry: own outstanding vmem = A(t)'s 2 gld_lds.
  for (int t = 0; t < NT; ++t) {
    const int cur = t & 1;
    if (t + 1 < NT) {
      LOADB(t + 1);             // +8
      ISSUE_A(t + 1, cur ^ 1);  // +2 -> outstanding = A(t)2(oldest) + 10
      WAIT_VM10_F;              // FIFO retire: drains exactly own A(t)
    } else {
      WAIT_VM0_F;
    }
    BARRIER_SYNC;  // collective: all waves' tile-t A landed; Bs[cur] written
#pragma unroll
    for (int s = 0; s < 2; ++s) {
      short8 a[4], b[2];
#pragma unroll
      for (int i = 0; i < 4; i++)
        a[i] = *(const short8*)&As[cur][s][(i * 16 + col) * 32 + quad * 8];
#pragma unroll
      for (int j = 0; j < 2; j++) {
        int row = wn + j * 16 + col;
        b[j] = *(const short8*)((const char*)&Bs[cur][s][0] +
                                ((row * 64 + quad * 16) ^ (((row >> 2) & 15) << 4)));
      }
#pragma unroll
      for (int i = 0; i < 4; i++)
#pragma unroll
        for (int j = 0; j < 2; j++)
          acc[i][j] = __builtin_amdgcn_mfma_f32_16x16x32_bf16(b[j], a[i], acc[i][j], 0, 0, 0);
    }
    if (t + 1 < NT) {
      WRITEB(cur ^ 1);  // compiler vmcnt(2) for bv(t+1); A(t+1) stays flying
      WAIT_LGKM0_F;     // publish ds_writes before releasing readers
    }
    BARRIER_SYNC;  // separates compute(t) readers from iter-t+1 buf writers
  }
#undef ISSUE_A
#undef LOADB
#undef WRITEB

#pragma unroll
  for (int i = 0; i < 4; i++) {
    int m = m0 + i * 16 + col;
#pragma unroll
    for (int j = 0; j < 2; j++) {
      int n = n0 + wn + j * 16 + quad * 4;
      ushort4 o;
      o.x = f2bf(acc[i][j][0]); o.y = f2bf(acc[i][j][1]);
      o.z = f2bf(acc[i][j][2]); o.w = f2bf(acc[i][j][3]);
      *(ushort4*)(C + (size_t)m * 12288 + n) = o;
    }
  }
}

// ---------------------------------------------------------------------------
// mm1_bt: G = projb @ WEb^T.  (r5/r10-proven, unchanged.)  Tile 128m x 64n,
// BK=64 dbuf, 48 KB LDS; grid 8x64 = 512 = 2/CU exact.  XCD-aware bijective
// remap: same-yb blocks share one A-panel on one XCD.
// mfma(a,b): lane regs span k (G's contiguous dim) -> ushort4 scatter into
// bf16 G[s1][s2][16], guarded < 500.
// ---------------------------------------------------------------------------
__global__ __launch_bounds__(256, 2) void mm1_bt(const ushort_t* __restrict__ A,
                                                 const ushort_t* __restrict__ Bm,
                                                 ushort_t* __restrict__ G) {
  __shared__ ushort_t As[2][2][128 * 32];  // 32 KB
  __shared__ ushort_t Bs[2][2][64 * 32];   // 16 KB
  const int tid = threadIdx.x;
  const int wave = tid >> 6, lane = tid & 63;
  // lin bits [b8..b0]: yb = {b2 b1 b0 b8 b7 b6}, xb = {b5 b4 b3}
  const int lin = blockIdx.x + (blockIdx.y << 3);
  const int yb = ((lin & 7) << 3) | (lin >> 6);
  const int xb = (lin >> 3) & 7;
  const int m0 = yb * 128, n0 = xb * 64;
  const int wm = (wave & 1) * 64, wn = (wave >> 1) * 32;
  const int col = lane & 15, quad = lane >> 4;

  floatx4 acc[4][2];
#pragma unroll
  for (int i = 0; i < 4; i++)
#pragma unroll
    for (int j = 0; j < 2; j++)
#pragma unroll
      for (int e = 0; e < 4; e++) acc[i][j][e] = 0.f;

  const int lrow = lane >> 2, scol = (lane & 3) * 8;
  const ushort_t* ga0 = A + (size_t)(m0 + wave * 32 + lrow) * D_ + scol;
  const ushort_t* gb0 = Bm + (size_t)(n0 + wave * 16 + lrow) * D_ + scol;
  const int aoff = (wave * 32) * 32;
  const int boff = (wave * 16) * 32;

#define ISSUE_TILE1(t_, buf_)                                                  \
  do {                                                                         \
    _Pragma("unroll") for (int s_ = 0; s_ < 2; s_++) {                         \
      const ushort_t* ga = ga0 + (t_)*64 + s_ * 32;                            \
      const ushort_t* gb = gb0 + (t_)*64 + s_ * 32;                            \
      GLD_LDS16(ga, &As[buf_][s_][aoff]);                                      \
      GLD_LDS16(ga + 16 * D_, &As[buf_][s_][aoff + 16 * 32]);                  \
      GLD_LDS16(gb, &Bs[buf_][s_][boff]);                                      \
    }                                                                          \
  } while (0)

  ISSUE_TILE1(0, 0);
  for (int t = 0; t < NT; ++t) {
    const int cur = t & 1;
    if (t + 1 < NT) {
      ISSUE_TILE1(t + 1, cur ^ 1);
      WAIT_VM6;
    } else {
      WAIT_VM0;
    }
    ASM_BARRIER;
#pragma unroll
    for (int s = 0; s < 2; ++s) {
      short8 a[4], b[2];
#pragma unroll
      for (int i = 0; i < 4; i++)
        a[i] = *(const short8*)&As[cur][s][(wm + i * 16 + col) * 32 + quad * 8];
#pragma unroll
      for (int j = 0; j < 2; j++)
        b[j] = *(const short8*)&Bs[cur][s][(wn + j * 16 + col) * 32 + quad * 8];
#pragma unroll
      for (int i = 0; i < 4; i++)
#pragma unroll
        for (int j = 0; j < 2; j++)
          acc[i][j] = __builtin_amdgcn_mfma_f32_16x16x32_bf16(a[i], b[j], acc[i][j], 0, 0, 0);
    }
    ASM_BARRIER;
  }
#undef ISSUE_TILE1

  // G[s1][s2][16] bf16: m = (s1,k); 16x16 m-tile is one s1, k = quad*4+reg
#pragma unroll
  for (int i = 0; i < 4; i++) {
    int s1 = (m0 + wm + i * 16) >> 4;
#pragma unroll
    for (int j = 0; j < 2; j++) {
      int s2 = n0 + wn + j * 16 + col;
      if (s1 < S_ && s2 < S_) {
        ushort4 o;
        o.x = f2bf(acc[i][j][0]); o.y = f2bf(acc[i][j][1]);
        o.z = f2bf(acc[i][j][2]); o.w = f2bf(acc[i][j][3]);
        *(ushort4*)(G + (((size_t)s1 * S_ + s2) << 4) + quad * 4) = o;
      }
    }
  }
}

// ---------------------------------------------------------------------------
// lse_kernel: out[r][k] = logsumexp over valid (p,q) of G[idx1[r,p]][idx2[r,q]][k]
// One block per r; 512 threads; 1-exp online update.  (r5/r10-proven.)
// ---------------------------------------------------------------------------
__global__ __launch_bounds__(512) void lse_kernel(const ushort_t* __restrict__ G,
                                                  const int* __restrict__ idx1,
                                                  const int* __restrict__ idx2,
                                                  const float* __restrict__ mask1,
                                                  const float* __restrict__ mask2,
                                                  float* __restrict__ out) {
  const int r = blockIdx.x;
  const int tid = threadIdx.x;
  __shared__ int b1[P_], b2[P_];
  __shared__ int s_len1, s_len2;
  __shared__ float wmx[8][K_], wsum[8][K_];

  if (tid < 64) {
    float mv = mask1[r * P_ + tid];
    unsigned long long bal = __ballot(mv > 0.5f);
    if (tid == 0) s_len1 = (int)__popcll(bal);
    b1[tid] = idx1[r * P_ + tid] * (S_ * K_);
  } else if (tid < 128) {
    int q = tid - 64;
    float mv = mask2[r * P_ + q];
    unsigned long long bal = __ballot(mv > 0.5f);
    if (q == 0) s_len2 = (int)__popcll(bal);
    b2[q] = idx2[r * P_ + q] * K_;
  }
  __syncthreads();
  const int len2 = s_len2;
  const int total = s_len1 * len2;

  float m[K_], s[K_];
#pragma unroll
  for (int k = 0; k < K_; k++) { m[k] = -3.0e38f; s[k] = 0.f; }

  for (int i = tid; i < total; i += 512) {
    int p = i / len2;
    int q = i - p * len2;
    const uint4* g4 = (const uint4*)(G + b1[p] + b2[q]);  // 16 bf16 = 32 B
    uint4 w0 = g4[0], w1 = g4[1];
    unsigned int uu[8] = {w0.x, w0.y, w0.z, w0.w, w1.x, w1.y, w1.z, w1.w};
    float z[K_];
#pragma unroll
    for (int h = 0; h < 8; h++) {
      z[2 * h + 0] = __uint_as_float(uu[h] << 16);
      z[2 * h + 1] = __uint_as_float(uu[h] & 0xffff0000u);
    }
#pragma unroll
    for (int k = 0; k < K_; k++) {
      float d = z[k] - m[k];
      float e = __expf(-fabsf(d));
      bool up = d > 0.f;
      s[k] = up ? __fmaf_rn(s[k], e, 1.f) : (s[k] + e);
      m[k] = up ? z[k] : m[k];
    }
  }

#pragma unroll
  for (int off = 1; off < 64; off <<= 1) {
#pragma unroll
    for (int k = 0; k < K_; k++) {
      float mo = __shfl_xor(m[k], off, 64);
      float so = __shfl_xor(s[k], off, 64);
      float d = mo - m[k];
      float e = __expf(-fabsf(d));
      bool up = d > 0.f;
      s[k] = up ? __fmaf_rn(s[k], e, so) : __fmaf_rn(so, e, s[k]);
      m[k] = up ? mo : m[k];
    }
  }
  const int wave = tid >> 6, lane = tid & 63;
  if (lane == 0) {
#pragma unroll
    for (int k = 0; k < K_; k++) { wmx[wave][k] = m[k]; wsum[wave][k] = s[k]; }
  }
  __syncthreads();
  if (tid < K_) {
    float M = -3.0e38f, Ssum = 0.f;
#pragma unroll
    for (int w = 0; w < 8; w++) {
      float mo = wmx[w][tid], so = wsum[w][tid];
      float d = mo - M;
      float e = __expf(-fabsf(d));
      bool up = d > 0.f;
      Ssum = up ? __fmaf_rn(Ssum, e, so) : __fmaf_rn(so, e, Ssum);
      M = up ? mo : M;
    }
    out[r * K_ + tid] = M + __logf(Ssum);
  }
}

// ---------------------------------------------------------------------------
extern "C" void kernel_launch(void* const* d_in, const int* in_sizes, int n_in,
                              void* d_out, int out_size, void* d_ws, size_t ws_size,
                              hipStream_t stream) {
  const float* WE    = (const float*)d_in[0];  // [500][768]
  const float* Wf    = (const float*)d_in[1];  // [768][16][768]
  const int*   idx1  = (const int*)d_in[2];
  const int*   idx2  = (const int*)d_in[3];
  const float* mask1 = (const float*)d_in[4];
  const float* mask2 = (const float*)d_in[5];
  float* out = (float*)d_out;                  // [256][16]

  // workspace: WEb [512][768] bf16 | projb [512][12288] bf16 (== [8192][768])
  //            | G [500][500][16] bf16   (~21.4 MB total, 16B-aligned)
  ushort_t* WEb   = (ushort_t*)d_ws;
  ushort_t* projb = WEb + (size_t)512 * 768;
  ushort_t* G     = projb + (size_t)512 * 12288;

  prep<<<384, 256, 0, stream>>>(WE, WEb);
  // proj[s][(k,e)] = WEb @ W : M=512, N=12288, tile 64x128, 768 blocks = 3/CU
  mm0_fused<<<dim3(96, 8), 256, 0, stream>>>(WEb, Wf, projb);
  // G[(s1,k)][s2] = projb @ WEb^T : M=8192, N=512, tile 128x64, 512 blocks
  mm1_bt<<<dim3(8, 64), 256, 0, stream>>>(projb, WEb, G);
  lse_kernel<<<R_, 512, 0, stream>>>(G, idx1, idx2, mask1, mask2, out);
}